// Round 6
// baseline (1486.186 us; speedup 1.0000x reference)
//
#include <hip/hip_runtime.h>
#include <math.h>

// Problem constants (fixed by setup_inputs)
#define NCH 128
#define IMW 640
#define IMH 480
#define HW (IMW * IMH)
#define THREADS 512
#define WPB (THREADS / 64)   // waves per block
#define GBLK 512             // fused blocks
#define TSTRIDE (3 * NCH)    // interleaved (pix, map, ch) stride = 384 floats
#define TPX 32               // transpose tile pixels
#define NTILE (HW / TPX)     // 9600 (divisible by 8 -> bijective XCD chunking)

// state layout in d_ws (doubles)
#define S_R    0   // 9: accepted R (row-major)
#define S_T    9   // 3: accepted t
#define S_RC   12  // 9: candidate R
#define S_TC   21  // 3: candidate t
#define S_LAM  24
#define S_LR   25
#define S_PREV 26
#define S_G    32  // 27: stashed Grad(6)+Hess-tri(21) at accepted pose
#define S_TOTAL 64

#define PCOLS 29            // 27 grad/hess + cost + count
#define PSTRIDE 32          // part row stride (doubles)

struct ProjR {
  float x, y, z;
  int pix;
  bool m;
};

__device__ __forceinline__ ProjR project_pt(const float* __restrict__ pts, int n,
                                            const float R[9], const float T[3],
                                            const float Kv[9]) {
  float px = pts[3 * n + 0], py = pts[3 * n + 1], pz = pts[3 * n + 2];
  ProjR o;
  o.x = R[0] * px + R[1] * py + R[2] * pz + T[0];
  o.y = R[3] * px + R[4] * py + R[5] * pz + T[1];
  o.z = R[6] * px + R[7] * py + R[8] * pz + T[2];
  float pr0 = Kv[0] * o.x + Kv[1] * o.y + Kv[2] * o.z;
  float pr1 = Kv[3] * o.x + Kv[4] * o.y + Kv[5] * o.z;
  float pr2 = Kv[6] * o.x + Kv[7] * o.y + Kv[8] * o.z;
  float u = fminf(fmaxf(pr0 / pr2, -1000000.0f), 1000000.0f);
  float v = fminf(fmaxf(pr1 / pr2, -1000000.0f), 1000000.0f);
  int p2x = (int)rintf(u) - 1;   // round-half-even matches jnp.round
  int p2y = (int)rintf(v) - 1;
  o.m = (p2x >= 0) && (p2y >= 0) && (p2x < IMW) && (p2y < IMH);
  int r = min(max(p2y, 0), IMH - 1);
  int c = min(max(p2x, 0), IMW - 1);
  o.pix = r * IMW + c;
  return o;
}

__device__ __forceinline__ void jac_rows(const ProjR& p, float fx, float fy,
                                         float A0[6], float A1[6]) {
  float Zs = (fabsf(p.z) > 1e-6f) ? p.z : 1e-6f;
  float iz = 1.0f / Zs;
  float j00 = fx * iz;
  float j02 = -fx * p.x * iz * iz;
  float j11 = fy * iz;
  float j12 = -fy * p.y * iz * iz;
  A0[0] = j00; A0[1] = 0.0f; A0[2] = j02;
  A0[3] = j02 * p.y; A0[4] = j00 * p.z - j02 * p.x; A0[5] = -j00 * p.y;
  A1[0] = 0.0f; A1[1] = j11; A1[2] = j12;
  A1[3] = -j11 * p.z + j12 * p.y; A1[4] = -j12 * p.x; A1[5] = j11 * p.x;
}

__global__ void init_kernel(const float* __restrict__ Rin,
                            const float* __restrict__ tin,
                            double* __restrict__ st, int* __restrict__ cnt) {
  int i = threadIdx.x;
  if (i < 9) { st[S_R + i] = (double)Rin[i]; st[S_RC + i] = (double)Rin[i]; }
  if (i < 3) { st[S_T + i] = (double)tin[i]; st[S_TC + i] = (double)tin[i]; }
  if (i == 0) { st[S_LAM] = 0.01; st[S_LR] = 1.0; st[S_PREV] = 0.0; }
  if (i < 16) cnt[i] = 0;
}

// ---- (C,H,W) -> interleaved (pix, map, ch) transpose ----
// One block stages ALL 3 maps for a 32-pixel tile in 48KB LDS, then writes
// its 48KB output region PERFECTLY stride-1 (out float4 index == linear in
// thread id). Bijective XCD chunking (9600%8==0): each XCD owns 1200
// consecutive tiles -> one contiguous ~59MB read/write span per XCD.
// LDS cell for logical [px][j] (j = map*32+c4): j ^ (px>>2) ^ (px&3)
//  -> write phase ~2-way (free), read phase conflict-free b128.
__global__ __launch_bounds__(512) void transpose3_kernel(
    const float* __restrict__ f, const float* __restrict__ gx,
    const float* __restrict__ gy, float* __restrict__ t) {
  __shared__ float4 l4[TPX * 96];  // 48 KB
  const int bx = blockIdx.x;
  const int tile = (bx & 7) * (NTILE / 8) + (bx >> 3);
  const int pix0 = tile * TPX;

  float4 v[6];
#pragma unroll
  for (int it = 0; it < 6; ++it) {
    int k = threadIdx.x + 512 * it;       // 0..3071
    int map = k >> 10;                    // 0..2
    int r = k & 1023;
    int c = r >> 3;                       // channel 0..127
    int g = r & 7;                        // float4 group (pixels 4g..4g+3)
    const float* in = (map == 0) ? f : (map == 1) ? gx : gy;
    v[it] = ((const float4*)(in + (size_t)c * HW + pix0))[g];
  }
#pragma unroll
  for (int it = 0; it < 6; ++it) {
    int k = threadIdx.x + 512 * it;
    int map = k >> 10;
    int r = k & 1023;
    int c = r >> 3, g = r & 7;
    int j = map * 32 + (c >> 2), e = c & 3;
    int jb = j ^ g;                       // (px>>2)==g for px=4g..4g+3
    ((float*)&l4[(4 * g + 0) * 96 + (jb ^ 0)])[e] = v[it].x;
    ((float*)&l4[(4 * g + 1) * 96 + (jb ^ 1)])[e] = v[it].y;
    ((float*)&l4[(4 * g + 2) * 96 + (jb ^ 2)])[e] = v[it].z;
    ((float*)&l4[(4 * g + 3) * 96 + (jb ^ 3)])[e] = v[it].w;
  }
  __syncthreads();
#pragma unroll
  for (int it = 0; it < 6; ++it) {
    int o = threadIdx.x + 512 * it;       // 0..3071, stride-1 output
    int px = o / 96, j = o % 96;
    float4 w = l4[px * 96 + (j ^ ((px >> 2) & 7) ^ (px & 3))];
    ((float4*)t)[(size_t)pix0 * 96 + o] = w;
  }
}

// ---- fused cost+grad at CANDIDATE pose + in-kernel reduce/accept/solve ----
// LM identity: grad/Hess is pose-pure; accept adopts this pass's sums,
// reject reuses the stash. Last-block-done: block partials via agent-scope
// atomic stores -> threadfence -> device counter; last block reduces,
// accepts/rejects, solves next candidate, writes out. 13 dispatches total.
template <bool TRANS>
__global__ __launch_bounds__(THREADS) void fused_kernel(
    const float* __restrict__ pts, const float* __restrict__ fref,
    const float* __restrict__ mf, const float* __restrict__ mgx,
    const float* __restrict__ mgy, const float* __restrict__ Kmat,
    double* __restrict__ st, double* __restrict__ part, int* __restrict__ cnt,
    float* __restrict__ out, int N, int pass) {
  const int lane = threadIdx.x & 63;
  const int wib  = threadIdx.x >> 6;
  const int gw = blockIdx.x * WPB + wib;
  const int nw = gridDim.x * WPB;
  const int half = lane >> 5;
  const int hl   = lane & 31;

  float R[9], T[3], Kv[9];
#pragma unroll
  for (int i = 0; i < 9; ++i) { R[i] = (float)st[S_RC + i]; Kv[i] = Kmat[i]; }
#pragma unroll
  for (int i = 0; i < 3; ++i) T[i] = (float)st[S_TC + i];
  const float fx = Kv[0], fy = Kv[4];

  float hacc[27];
#pragma unroll
  for (int j = 0; j < 27; ++j) hacc[j] = 0.0f;
  double csum = 0.0;
  float cntf = 0.0f;

  for (int base = gw * 2; base < N; base += 2 * nw) {
    const int n = min(base + half, N - 1);
    ProjR p = project_pt(pts, n, R, T, Kv);
    const float m = (p.m && (base + half) < N) ? 1.0f : 0.0f;
    if (__all(m == 0.0f)) continue;

    float A0[6], A1[6];
    jac_rows(p, fx, fy, A0, A1);

    float e0, e1, e2, e3, gxx, gxy, gyy, gxe, gye;
    if (TRANS) {
      const float4* t4 = (const float4*)mf;
      const size_t b = (size_t)p.pix * 96 + hl;
      float4 fv = t4[b];
      float4 gv = t4[b + 32];
      float4 hv = t4[b + 64];
      float4 rv = ((const float4*)fref)[(size_t)n * (NCH / 4) + hl];
      e0 = fv.x - rv.x; e1 = fv.y - rv.y; e2 = fv.z - rv.z; e3 = fv.w - rv.w;
      gxx = gv.x * gv.x + gv.y * gv.y + gv.z * gv.z + gv.w * gv.w;
      gxy = gv.x * hv.x + gv.y * hv.y + gv.z * hv.z + gv.w * hv.w;
      gyy = hv.x * hv.x + hv.y * hv.y + hv.z * hv.z + hv.w * hv.w;
      gxe = gv.x * e0 + gv.y * e1 + gv.z * e2 + gv.w * e3;
      gye = hv.x * e0 + hv.y * e1 + hv.z * e2 + hv.w * e3;
    } else {
      const int c0 = hl * 4;
      const size_t bb = (size_t)p.pix;
      float f0 = mf[(size_t)(c0 + 0) * HW + bb];
      float f1 = mf[(size_t)(c0 + 1) * HW + bb];
      float f2 = mf[(size_t)(c0 + 2) * HW + bb];
      float f3 = mf[(size_t)(c0 + 3) * HW + bb];
      float gx0 = mgx[(size_t)(c0 + 0) * HW + bb];
      float gx1 = mgx[(size_t)(c0 + 1) * HW + bb];
      float gx2 = mgx[(size_t)(c0 + 2) * HW + bb];
      float gx3 = mgx[(size_t)(c0 + 3) * HW + bb];
      float gy0 = mgy[(size_t)(c0 + 0) * HW + bb];
      float gy1 = mgy[(size_t)(c0 + 1) * HW + bb];
      float gy2 = mgy[(size_t)(c0 + 2) * HW + bb];
      float gy3 = mgy[(size_t)(c0 + 3) * HW + bb];
      float4 rv = ((const float4*)fref)[(size_t)n * (NCH / 4) + hl];
      e0 = f0 - rv.x; e1 = f1 - rv.y; e2 = f2 - rv.z; e3 = f3 - rv.w;
      gxx = gx0 * gx0 + gx1 * gx1 + gx2 * gx2 + gx3 * gx3;
      gxy = gx0 * gy0 + gx1 * gy1 + gx2 * gy2 + gx3 * gy3;
      gyy = gy0 * gy0 + gy1 * gy1 + gy2 * gy2 + gy3 * gy3;
      gxe = gx0 * e0 + gx1 * e1 + gx2 * e2 + gx3 * e3;
      gye = gy0 * e0 + gy1 * e1 + gy2 * e2 + gy3 * e3;
    }

    gxx *= m; gxy *= m; gyy *= m; gxe *= m; gye *= m;
    csum += (double)(m * (e0 * e0 + e1 * e1 + e2 * e2 + e3 * e3));
    if (hl == 0) cntf += m;

#pragma unroll
    for (int k = 0; k < 6; ++k) hacc[k] += gxe * A0[k] + gye * A1[k];
    float u[6], v[6];
#pragma unroll
    for (int k = 0; k < 6; ++k) {
      u[k] = gxx * A0[k] + gxy * A1[k];
      v[k] = gxy * A0[k] + gyy * A1[k];
    }
    int q = 6;
#pragma unroll
    for (int k = 0; k < 6; ++k)
#pragma unroll
      for (int l = k; l < 6; ++l) {
        hacc[q] += u[k] * A0[l] + v[k] * A1[l];
        ++q;
      }
  }

  // wave reduce (double) + block reduce
  __shared__ double red[WPB][PCOLS];
#pragma unroll
  for (int j = 0; j < 27; ++j) {
    double d = (double)hacc[j];
#pragma unroll
    for (int off = 32; off > 0; off >>= 1) d += __shfl_xor(d, off);
    if (lane == 0) red[wib][j] = d;
  }
  {
    double cs = csum;
    float cf = cntf;
#pragma unroll
    for (int off = 32; off > 0; off >>= 1) {
      cs += __shfl_xor(cs, off);
      cf += __shfl_xor(cf, off);
    }
    if (lane == 0) { red[wib][27] = cs; red[wib][28] = (double)cf; }
  }
  __syncthreads();

  __shared__ int is_last_s;
  if (wib == 0) {
    if (lane < PCOLS) {
      double s = 0.0;
#pragma unroll
      for (int w = 0; w < WPB; ++w) s += red[w][lane];
      // agent-scope store: bypass non-coherent per-XCD caching for the reader
      __hip_atomic_store(&part[(size_t)blockIdx.x * PSTRIDE + lane], s,
                         __ATOMIC_RELAXED, __HIP_MEMORY_SCOPE_AGENT);
    }
    __threadfence();
    if (lane == 0) {
      int old = __hip_atomic_fetch_add(&cnt[pass], 1, __ATOMIC_ACQ_REL,
                                       __HIP_MEMORY_SCOPE_AGENT);
      is_last_s = (old == (int)gridDim.x - 1) ? 1 : 0;
    }
  }
  __syncthreads();
  if (!is_last_s) return;

  // ---- last block: reduce all partials ----
  __shared__ double redf[16][PCOLS];
  __shared__ double tot[PCOLS];
  {
    int q = threadIdx.x & 31;
    int chunk = threadIdx.x >> 5;  // 0..15
    if (q < PCOLS) {
      double s = 0.0;
      for (int b = chunk; b < (int)gridDim.x; b += 16)
        s += __hip_atomic_load(&part[(size_t)b * PSTRIDE + q],
                               __ATOMIC_RELAXED, __HIP_MEMORY_SCOPE_AGENT);
      redf[chunk][q] = s;
    }
  }
  __syncthreads();
  if (threadIdx.x < PCOLS) {
    double s = 0.0;
#pragma unroll
    for (int ch = 0; ch < 16; ++ch) s += redf[ch][threadIdx.x];
    tot[threadIdx.x] = s;
  }
  __syncthreads();
  if (threadIdx.x != 0) return;

  // ---- accept/reject + LM solve for next candidate (thread 0) ----
  {
    double nc = 0.5 * tot[27] / fmax(tot[28], 1.0);
    bool accept;
    if (pass == 0) {
      accept = true;
      st[S_PREV] = nc;
    } else {
      accept = (nc <= st[S_PREV]);
      double lam = st[S_LAM] * (accept ? 0.1 : 10.0);
      st[S_LAM] = fmin(fmax(lam, 1e-6), 1e4);
      st[S_LR] = accept ? 1.0 : fmin(fmax(0.1 * st[S_LR], 1e-3), 1.0);
      if (accept) st[S_PREV] = nc;
    }
    if (accept) {
      for (int i = 0; i < 9; ++i) st[S_R + i] = st[S_RC + i];
      for (int i = 0; i < 3; ++i) st[S_T + i] = st[S_TC + i];
      for (int j = 0; j < 27; ++j) st[S_G + j] = tot[j];
    }
    for (int i = 0; i < 9; ++i) out[i] = (float)st[S_R + i];
    for (int i = 0; i < 3; ++i) out[9 + i] = (float)st[S_T + i];

    double Grad[6], Hs[6][6];
    for (int j = 0; j < 6; ++j) Grad[j] = st[S_G + j];
    int qq = 0;
    for (int k = 0; k < 6; ++k)
      for (int l = k; l < 6; ++l) { Hs[k][l] = Hs[l][k] = st[S_G + 6 + qq]; ++qq; }
    double lam = st[S_LAM], lr = st[S_LR];
    double M[6][7];
    for (int i = 0; i < 6; ++i) {
      for (int j = 0; j < 6; ++j) M[i][j] = Hs[i][j];
      M[i][i] += lam * (Hs[i][i] + 1e-9);
      M[i][6] = Grad[i];
    }
    for (int c = 0; c < 6; ++c) {
      int piv = c;
      double mx = fabs(M[c][c]);
      for (int r = c + 1; r < 6; ++r) {
        double a = fabs(M[r][c]);
        if (a > mx) { mx = a; piv = r; }
      }
      if (piv != c)
        for (int j = 0; j < 7; ++j) {
          double tmp = M[c][j]; M[c][j] = M[piv][j]; M[piv][j] = tmp;
        }
      double pv = M[c][c];
      if (pv == 0.0) pv = 1e-30;
      for (int r = c + 1; r < 6; ++r) {
        double fq = M[r][c] / pv;
        for (int j = c; j < 7; ++j) M[r][j] -= fq * M[c][j];
      }
    }
    double xs[6];
    for (int i = 5; i >= 0; --i) {
      double vv = M[i][6];
      for (int j = i + 1; j < 6; ++j) vv -= M[i][j] * xs[j];
      double pv = M[i][i];
      if (pv == 0.0) pv = 1e-30;
      xs[i] = vv / pv;
    }
    double dt[3] = {-lr * xs[0], -lr * xs[1], -lr * xs[2]};
    double dw[3] = {-lr * xs[3], -lr * xs[4], -lr * xs[5]};
    double th2 = dw[0] * dw[0] + dw[1] * dw[1] + dw[2] * dw[2];
    double th = sqrt(th2 + 1e-24);
    double a, b;
    if (th < 1e-4) { a = 1.0 - th2 / 6.0; b = 0.5 - th2 / 24.0; }
    else { a = sin(th) / th; b = (1.0 - cos(th)) / (th2 + 1e-24); }
    double W[3][3] = {{0, -dw[2], dw[1]}, {dw[2], 0, -dw[0]}, {-dw[1], dw[0], 0}};
    double W2[3][3];
    for (int i = 0; i < 3; ++i)
      for (int j = 0; j < 3; ++j) {
        double s = 0.0;
        for (int k = 0; k < 3; ++k) s += W[i][k] * W[k][j];
        W2[i][j] = s;
      }
    double dr[3][3];
    for (int i = 0; i < 3; ++i)
      for (int j = 0; j < 3; ++j)
        dr[i][j] = ((i == j) ? 1.0 : 0.0) + a * W[i][j] + b * W2[i][j];
    for (int i = 0; i < 3; ++i) {
      for (int j = 0; j < 3; ++j) {
        double s = 0.0;
        for (int k = 0; k < 3; ++k) s += dr[i][k] * st[S_R + k * 3 + j];
        st[S_RC + i * 3 + j] = s;
      }
      double s = 0.0;
      for (int k = 0; k < 3; ++k) s += dr[i][k] * st[S_T + k];
      st[S_TC + i] = s + dt[i];
    }
  }
}

extern "C" void kernel_launch(void* const* d_in, const int* in_sizes, int n_in,
                              void* d_out, int out_size, void* d_ws, size_t ws_size,
                              hipStream_t stream) {
  const float* pts  = (const float*)d_in[0];
  const float* fref = (const float*)d_in[1];
  const float* fm   = (const float*)d_in[2];
  const float* gxm  = (const float*)d_in[3];
  const float* gym  = (const float*)d_in[4];
  const float* Kmat = (const float*)d_in[5];
  const float* Rin  = (const float*)d_in[6];
  const float* tin  = (const float*)d_in[7];
  const int N = in_sizes[0] / 3;

  double* st = (double*)d_ws;
  double* part = st + S_TOTAL;                      // GBLK*32 doubles
  int* cnt = (int*)(part + (size_t)GBLK * PSTRIDE); // 16 ints
  size_t int_end = (size_t)((char*)(cnt + 16) - (char*)d_ws);
  size_t tmap_off = (int_end + 15) & ~(size_t)15;
  float* tmap = (float*)((char*)d_ws + tmap_off);
  float* out = (float*)d_out;

  const size_t map_floats = (size_t)HW * NCH;       // 39.32 M
  const size_t need_fast = tmap_off + 3 * map_floats * sizeof(float) + 256;

  init_kernel<<<1, 512, 0, stream>>>(Rin, tin, st, cnt);

  if (ws_size >= need_fast) {
    transpose3_kernel<<<NTILE, 512, 0, stream>>>(fm, gxm, gym, tmap);
    for (int pass = 0; pass < 11; ++pass) {
      fused_kernel<true><<<GBLK, THREADS, 0, stream>>>(
          pts, fref, tmap, tmap, tmap, Kmat, st, part, cnt, out, N, pass);
    }
  } else {
    for (int pass = 0; pass < 11; ++pass) {
      fused_kernel<false><<<GBLK, THREADS, 0, stream>>>(
          pts, fref, fm, gxm, gym, Kmat, st, part, cnt, out, N, pass);
    }
  }
}

// Round 7
// 974.004 us; speedup vs baseline: 1.5259x; 1.5259x over previous
//
#include <hip/hip_runtime.h>
#include <math.h>

// Problem constants (fixed by setup_inputs)
#define NCH 128
#define IMW 640
#define IMH 480
#define HW (IMW * IMH)
#define THREADS 512
#define WPB (THREADS / 64)   // waves per block
#define GBLK 512             // fused blocks
#define TSTRIDE (3 * NCH)    // interleaved (pix, map, ch) stride = 384 floats
#define TPX 32               // transpose tile pixels
#define NTILE (HW / TPX)     // 9600 (divisible by 8 -> bijective XCD chunking)
#define NBUCK (HW / 64)      // 4800 sort buckets

// state layout in d_ws (doubles)
#define S_R    0
#define S_T    9
#define S_RC   12
#define S_TC   21
#define S_LAM  24
#define S_LR   25
#define S_PREV 26
#define S_G    32  // 27: stashed Grad(6)+Hess-tri(21) at accepted pose
#define S_TOTAL 64

#define PCOLS 29   // 27 grad/hess + cost + count

__device__ __forceinline__ float sel6(int k, float v0, float v1, float v2,
                                      float v3, float v4, float v5) {
  float r = v0;
  r = (k == 1) ? v1 : r;
  r = (k == 2) ? v2 : r;
  r = (k == 3) ? v3 : r;
  r = (k == 4) ? v4 : r;
  r = (k == 5) ? v5 : r;
  return r;
}

struct ProjR {
  float x, y, z;
  int pix;
  bool m;
};

__device__ __forceinline__ ProjR project_pt(const float* __restrict__ pts, int n,
                                            const float R[9], const float T[3],
                                            const float Kv[9]) {
  float px = pts[3 * n + 0], py = pts[3 * n + 1], pz = pts[3 * n + 2];
  ProjR o;
  o.x = R[0] * px + R[1] * py + R[2] * pz + T[0];
  o.y = R[3] * px + R[4] * py + R[5] * pz + T[1];
  o.z = R[6] * px + R[7] * py + R[8] * pz + T[2];
  float pr0 = Kv[0] * o.x + Kv[1] * o.y + Kv[2] * o.z;
  float pr1 = Kv[3] * o.x + Kv[4] * o.y + Kv[5] * o.z;
  float pr2 = Kv[6] * o.x + Kv[7] * o.y + Kv[8] * o.z;
  float u = fminf(fmaxf(pr0 / pr2, -1000000.0f), 1000000.0f);
  float v = fminf(fmaxf(pr1 / pr2, -1000000.0f), 1000000.0f);
  int p2x = (int)rintf(u) - 1;   // round-half-even matches jnp.round
  int p2y = (int)rintf(v) - 1;
  o.m = (p2x >= 0) && (p2y >= 0) && (p2x < IMW) && (p2y < IMH);
  int r = min(max(p2y, 0), IMH - 1);
  int c = min(max(p2x, 0), IMW - 1);
  o.pix = r * IMW + c;
  return o;
}

__device__ __forceinline__ void jac_rows(const ProjR& p, float fx, float fy,
                                         float A0[6], float A1[6]) {
  float Zs = (fabsf(p.z) > 1e-6f) ? p.z : 1e-6f;
  float iz = 1.0f / Zs;
  float j00 = fx * iz;
  float j02 = -fx * p.x * iz * iz;
  float j11 = fy * iz;
  float j12 = -fy * p.y * iz * iz;
  A0[0] = j00; A0[1] = 0.0f; A0[2] = j02;
  A0[3] = j02 * p.y; A0[4] = j00 * p.z - j02 * p.x; A0[5] = -j00 * p.y;
  A1[0] = 0.0f; A1[1] = j11; A1[2] = j12;
  A1[3] = -j11 * p.z + j12 * p.y; A1[4] = -j12 * p.x; A1[5] = j11 * p.x;
}

__global__ void init_kernel(const float* __restrict__ Rin,
                            const float* __restrict__ tin,
                            double* __restrict__ st, int* __restrict__ hist) {
  if (blockIdx.x == 0) {
    int i = threadIdx.x;
    if (i < 9) { st[S_R + i] = (double)Rin[i]; st[S_RC + i] = (double)Rin[i]; }
    if (i < 3) { st[S_T + i] = (double)tin[i]; st[S_TC + i] = (double)tin[i]; }
    if (i == 0) { st[S_LAM] = 0.01; st[S_LR] = 1.0; st[S_PREV] = 0.0; }
  }
  int gid = blockIdx.x * blockDim.x + threadIdx.x;
  for (int i = gid; i < NBUCK; i += gridDim.x * blockDim.x) hist[i] = 0;
}

// ---- sort A: keys (clamped pixel at INIT pose) + bucket histogram ----
__global__ __launch_bounds__(256) void sort_key_kernel(
    const float* __restrict__ pts, const float* __restrict__ Rin,
    const float* __restrict__ tin, const float* __restrict__ Kmat,
    int* __restrict__ keys, int* __restrict__ hist, int N) {
  int n = blockIdx.x * 256 + threadIdx.x;
  if (n >= N) return;
  float R[9], T[3], Kv[9];
#pragma unroll
  for (int i = 0; i < 9; ++i) { R[i] = Rin[i]; Kv[i] = Kmat[i]; }
#pragma unroll
  for (int i = 0; i < 3; ++i) T[i] = tin[i];
  ProjR p = project_pt(pts, n, R, T, Kv);
  keys[n] = p.pix;
  atomicAdd(&hist[p.pix >> 6], 1);
}

// ---- sort B: single-block exclusive scan of bucket counts ----
__global__ __launch_bounds__(512) void sort_scan_kernel(
    const int* __restrict__ hist, int* __restrict__ offs) {
  __shared__ int tsum[512];
  const int C = (NBUCK + 511) / 512;  // 10
  int t = threadIdx.x;
  int local[C];
  int s = 0;
#pragma unroll
  for (int j = 0; j < C; ++j) {
    int idx = t * C + j;
    int v = (idx < NBUCK) ? hist[idx] : 0;
    local[j] = s;
    s += v;
  }
  tsum[t] = s;
  __syncthreads();
  for (int off = 1; off < 512; off <<= 1) {
    int y = (t >= off) ? tsum[t - off] : 0;
    __syncthreads();
    tsum[t] += y;
    __syncthreads();
  }
  int base = (t == 0) ? 0 : tsum[t - 1];
#pragma unroll
  for (int j = 0; j < C; ++j) {
    int idx = t * C + j;
    if (idx < NBUCK) offs[idx] = base + local[j];
  }
}

// ---- sort C: scatter point ids into pixel-bucket order ----
__global__ __launch_bounds__(256) void sort_scatter_kernel(
    const int* __restrict__ keys, int* __restrict__ offs,
    int* __restrict__ order, int N) {
  int n = blockIdx.x * 256 + threadIdx.x;
  if (n >= N) return;
  int b = keys[n] >> 6;
  int pos = atomicAdd(&offs[b], 1);
  order[pos] = n;
}

// ---- physically permute fref and pts into sorted order (once) ----
// After this, EVERY per-pass stream (tmap gathers, fref, pts) is monotone:
// no random DRAM-row/TLB access remains in the iteration loop.
__global__ __launch_bounds__(256) void permute_kernel(
    const float* __restrict__ pts, const float* __restrict__ fref,
    const int* __restrict__ order, float* __restrict__ pts_s,
    float* __restrict__ fref_s, int N) {
  int gid = blockIdx.x * 256 + threadIdx.x;
  int tot4 = N * (NCH / 4);
  for (int idx = gid; idx < tot4; idx += gridDim.x * 256) {
    int i = idx >> 5, c4 = idx & 31;
    int n = order[i];  // broadcast within 32-lane group
    ((float4*)fref_s)[(size_t)i * 32 + c4] =
        ((const float4*)fref)[(size_t)n * 32 + c4];
  }
  int tot3 = N * 3;
  for (int idx = gid; idx < tot3; idx += gridDim.x * 256) {
    int i = idx / 3, r = idx - i * 3;
    pts_s[idx] = pts[3 * order[i] + r];
  }
}

// ---- (C,H,W) -> interleaved (pix, map, ch) transpose (R6: conflict-free,
// stride-1 writes, XCD-chunked; pinned at ~216us = DRAM-granularity bound) ----
__global__ __launch_bounds__(512) void transpose3_kernel(
    const float* __restrict__ f, const float* __restrict__ gx,
    const float* __restrict__ gy, float* __restrict__ t) {
  __shared__ float4 l4[TPX * 96];  // 48 KB
  const int bx = blockIdx.x;
  const int tile = (bx & 7) * (NTILE / 8) + (bx >> 3);
  const int pix0 = tile * TPX;

  float4 v[6];
#pragma unroll
  for (int it = 0; it < 6; ++it) {
    int k = threadIdx.x + 512 * it;
    int map = k >> 10;
    int r = k & 1023;
    int c = r >> 3;
    int g = r & 7;
    const float* in = (map == 0) ? f : (map == 1) ? gx : gy;
    v[it] = ((const float4*)(in + (size_t)c * HW + pix0))[g];
  }
#pragma unroll
  for (int it = 0; it < 6; ++it) {
    int k = threadIdx.x + 512 * it;
    int map = k >> 10;
    int r = k & 1023;
    int c = r >> 3, g = r & 7;
    int j = map * 32 + (c >> 2), e = c & 3;
    int jb = j ^ g;
    ((float*)&l4[(4 * g + 0) * 96 + (jb ^ 0)])[e] = v[it].x;
    ((float*)&l4[(4 * g + 1) * 96 + (jb ^ 1)])[e] = v[it].y;
    ((float*)&l4[(4 * g + 2) * 96 + (jb ^ 2)])[e] = v[it].z;
    ((float*)&l4[(4 * g + 3) * 96 + (jb ^ 3)])[e] = v[it].w;
  }
  __syncthreads();
#pragma unroll
  for (int it = 0; it < 6; ++it) {
    int o = threadIdx.x + 512 * it;
    int px = o / 96, j = o % 96;
    float4 w = l4[px * 96 + (j ^ ((px >> 2) & 7) ^ (px & 3))];
    ((float4*)t)[(size_t)pix0 * 96 + o] = w;
  }
}

// ---- fused cost+grad at CANDIDATE pose (R3 interior: 1 point/wave,
// float2 loads, per-point 5-quantity shuffle reduce -> LOW VGPR / max
// occupancy, which R3-vs-R4 showed is the controlling variable) ----
// LM identity: accept adopts this pass's sums; reject reuses the stash.
template <bool TRANS>
__global__ __launch_bounds__(THREADS) void fused_kernel(
    const float* __restrict__ pts, const float* __restrict__ fref,
    const float* __restrict__ mf, const float* __restrict__ mgx,
    const float* __restrict__ mgy, const float* __restrict__ Kmat,
    const double* __restrict__ st, double* __restrict__ part, int N) {
  const int lane = threadIdx.x & 63;
  const int wib = threadIdx.x >> 6;
  const int gw = blockIdx.x * WPB + wib;
  const int nw = gridDim.x * WPB;

  float R[9], T[3], Kv[9];
#pragma unroll
  for (int i = 0; i < 9; ++i) { R[i] = (float)st[S_RC + i]; Kv[i] = Kmat[i]; }
#pragma unroll
  for (int i = 0; i < 3; ++i) T[i] = (float)st[S_TC + i];
  const float fx = Kv[0], fy = Kv[4];

  int kq = 0, lq = 0;
  if (lane < 6) {
    kq = lane; lq = lane;
  } else if (lane < 27) {
    int q = lane - 6, k = 0;
    while (q >= 6 - k) { q -= 6 - k; ++k; }
    kq = k; lq = k + q;
  }

  double acc = 0.0, csum = 0.0, cnt = 0.0;

  for (int n = gw; n < N; n += nw) {
    ProjR p = project_pt(pts, n, R, T, Kv);
    if (!p.m) continue;  // wave-uniform
    float A0[6], A1[6];
    jac_rows(p, fx, fy, A0, A1);

    float e0, e1, gx0, gx1, gy0, gy1;
    if (TRANS) {
      const size_t base = (size_t)p.pix * TSTRIDE + 2 * lane;
      float2 f  = *(const float2*)(mf + base);
      float2 gx = *(const float2*)(mf + base + NCH);
      float2 gy = *(const float2*)(mf + base + 2 * NCH);
      float2 fr = *(const float2*)(fref + (size_t)n * NCH + 2 * lane);
      e0 = f.x - fr.x; e1 = f.y - fr.y;
      gx0 = gx.x; gx1 = gx.y; gy0 = gy.x; gy1 = gy.y;
    } else {
      const size_t base = (size_t)p.pix;
      const int c0 = lane, c1 = lane + 64;
      float f0 = mf[(size_t)c0 * HW + base], f1 = mf[(size_t)c1 * HW + base];
      gx0 = mgx[(size_t)c0 * HW + base]; gx1 = mgx[(size_t)c1 * HW + base];
      gy0 = mgy[(size_t)c0 * HW + base]; gy1 = mgy[(size_t)c1 * HW + base];
      float r0 = fref[(size_t)n * NCH + c0], r1 = fref[(size_t)n * NCH + c1];
      e0 = f0 - r0; e1 = f1 - r1;
    }

    csum += (double)(e0 * e0 + e1 * e1);
    if (lane == 0) cnt += 1.0;

    float sxx = gx0 * gx0 + gx1 * gx1;
    float sxy = gx0 * gy0 + gx1 * gy1;
    float syy = gy0 * gy0 + gy1 * gy1;
    float sxe = gx0 * e0 + gx1 * e1;
    float sye = gy0 * e0 + gy1 * e1;
#pragma unroll
    for (int off = 32; off > 0; off >>= 1) {
      sxx += __shfl_xor(sxx, off);
      sxy += __shfl_xor(sxy, off);
      syy += __shfl_xor(syy, off);
      sxe += __shfl_xor(sxe, off);
      sye += __shfl_xor(sye, off);
    }
    float a0k = sel6(kq, A0[0], A0[1], A0[2], A0[3], A0[4], A0[5]);
    float a1k = sel6(kq, A1[0], A1[1], A1[2], A1[3], A1[4], A1[5]);
    float a0l = sel6(lq, A0[0], A0[1], A0[2], A0[3], A0[4], A0[5]);
    float a1l = sel6(lq, A1[0], A1[1], A1[2], A1[3], A1[4], A1[5]);
    float contrib;
    if (lane < 6)
      contrib = sxe * a0k + sye * a1k;
    else
      contrib = sxx * a0k * a0l + sxy * (a0k * a1l + a1k * a0l) +
                syy * a1k * a1l;
    if (lane < 27) acc += (double)contrib;
  }

#pragma unroll
  for (int off = 32; off > 0; off >>= 1) {
    csum += __shfl_xor(csum, off);
    cnt += __shfl_xor(cnt, off);
  }

  __shared__ double red[WPB][PCOLS];
  if (lane < 27) red[wib][lane] = acc;
  if (lane == 0) { red[wib][27] = csum; red[wib][28] = cnt; }
  __syncthreads();
  if (wib == 0 && lane < PCOLS) {
    double s = 0.0;
#pragma unroll
    for (int w = 0; w < WPB; ++w) s += red[w][lane];
    part[(size_t)blockIdx.x * PCOLS + lane] = s;
  }
}

// Reduce partials; accept/reject; stash grads on accept; LM solve next
// candidate with UPDATED lambda/lr; write output pose.
__global__ void update_solve_kernel(const double* __restrict__ part, int GB,
                                    double* __restrict__ st,
                                    float* __restrict__ out, int is_init) {
  __shared__ double red[16][PCOLS];
  __shared__ double tot[PCOLS];
  int q = threadIdx.x & 31;
  int chunk = threadIdx.x >> 5;
  if (q < PCOLS) {
    double s = 0.0;
    for (int b = chunk; b < GB; b += 16) s += part[(size_t)b * PCOLS + q];
    red[chunk][q] = s;
  }
  __syncthreads();
  if (threadIdx.x < PCOLS) {
    double t = 0.0;
#pragma unroll
    for (int ch = 0; ch < 16; ++ch) t += red[ch][threadIdx.x];
    tot[threadIdx.x] = t;
  }
  __syncthreads();
  if (threadIdx.x == 0) {
    double nc = 0.5 * tot[27] / fmax(tot[28], 1.0);
    bool accept;
    if (is_init) {
      accept = true;
      st[S_PREV] = nc;
    } else {
      accept = (nc <= st[S_PREV]);
      double lam = st[S_LAM] * (accept ? 0.1 : 10.0);
      st[S_LAM] = fmin(fmax(lam, 1e-6), 1e4);
      st[S_LR] = accept ? 1.0 : fmin(fmax(0.1 * st[S_LR], 1e-3), 1.0);
      if (accept) st[S_PREV] = nc;
    }
    if (accept) {
      for (int i = 0; i < 9; ++i) st[S_R + i] = st[S_RC + i];
      for (int i = 0; i < 3; ++i) st[S_T + i] = st[S_TC + i];
      for (int j = 0; j < 27; ++j) st[S_G + j] = tot[j];
    }
    for (int i = 0; i < 9; ++i) out[i] = (float)st[S_R + i];
    for (int i = 0; i < 3; ++i) out[9 + i] = (float)st[S_T + i];

    double Grad[6], Hs[6][6];
    for (int j = 0; j < 6; ++j) Grad[j] = st[S_G + j];
    int qq = 0;
    for (int k = 0; k < 6; ++k)
      for (int l = k; l < 6; ++l) { Hs[k][l] = Hs[l][k] = st[S_G + 6 + qq]; ++qq; }
    double lam = st[S_LAM], lr = st[S_LR];
    double M[6][7];
    for (int i = 0; i < 6; ++i) {
      for (int j = 0; j < 6; ++j) M[i][j] = Hs[i][j];
      M[i][i] += lam * (Hs[i][i] + 1e-9);
      M[i][6] = Grad[i];
    }
    for (int c = 0; c < 6; ++c) {
      int piv = c;
      double mx = fabs(M[c][c]);
      for (int r = c + 1; r < 6; ++r) {
        double a = fabs(M[r][c]);
        if (a > mx) { mx = a; piv = r; }
      }
      if (piv != c)
        for (int j = 0; j < 7; ++j) {
          double tmp = M[c][j]; M[c][j] = M[piv][j]; M[piv][j] = tmp;
        }
      double pv = M[c][c];
      if (pv == 0.0) pv = 1e-30;
      for (int r = c + 1; r < 6; ++r) {
        double f = M[r][c] / pv;
        for (int j = c; j < 7; ++j) M[r][j] -= f * M[c][j];
      }
    }
    double xs[6];
    for (int i = 5; i >= 0; --i) {
      double v = M[i][6];
      for (int j = i + 1; j < 6; ++j) v -= M[i][j] * xs[j];
      double pv = M[i][i];
      if (pv == 0.0) pv = 1e-30;
      xs[i] = v / pv;
    }
    double dt[3] = {-lr * xs[0], -lr * xs[1], -lr * xs[2]};
    double dw[3] = {-lr * xs[3], -lr * xs[4], -lr * xs[5]};
    double th2 = dw[0] * dw[0] + dw[1] * dw[1] + dw[2] * dw[2];
    double th = sqrt(th2 + 1e-24);
    double a, b;
    if (th < 1e-4) { a = 1.0 - th2 / 6.0; b = 0.5 - th2 / 24.0; }
    else { a = sin(th) / th; b = (1.0 - cos(th)) / (th2 + 1e-24); }
    double W[3][3] = {{0, -dw[2], dw[1]}, {dw[2], 0, -dw[0]}, {-dw[1], dw[0], 0}};
    double W2[3][3];
    for (int i = 0; i < 3; ++i)
      for (int j = 0; j < 3; ++j) {
        double s = 0.0;
        for (int k = 0; k < 3; ++k) s += W[i][k] * W[k][j];
        W2[i][j] = s;
      }
    double dr[3][3];
    for (int i = 0; i < 3; ++i)
      for (int j = 0; j < 3; ++j)
        dr[i][j] = ((i == j) ? 1.0 : 0.0) + a * W[i][j] + b * W2[i][j];
    for (int i = 0; i < 3; ++i) {
      for (int j = 0; j < 3; ++j) {
        double s = 0.0;
        for (int k = 0; k < 3; ++k) s += dr[i][k] * st[S_R + k * 3 + j];
        st[S_RC + i * 3 + j] = s;
      }
      double s = 0.0;
      for (int k = 0; k < 3; ++k) s += dr[i][k] * st[S_T + k];
      st[S_TC + i] = s + dt[i];
    }
  }
}

extern "C" void kernel_launch(void* const* d_in, const int* in_sizes, int n_in,
                              void* d_out, int out_size, void* d_ws, size_t ws_size,
                              hipStream_t stream) {
  const float* pts  = (const float*)d_in[0];
  const float* fref = (const float*)d_in[1];
  const float* fm   = (const float*)d_in[2];
  const float* gxm  = (const float*)d_in[3];
  const float* gym  = (const float*)d_in[4];
  const float* Kmat = (const float*)d_in[5];
  const float* Rin  = (const float*)d_in[6];
  const float* tin  = (const float*)d_in[7];
  const int N = in_sizes[0] / 3;

  double* st = (double*)d_ws;
  double* part = st + S_TOTAL;
  int* keys  = (int*)(part + (size_t)GBLK * PCOLS);
  int* order = keys + N;
  int* hist  = order + N;
  int* offs  = hist + NBUCK;
  size_t int_end = (size_t)((char*)(offs + NBUCK) - (char*)d_ws);

  const size_t map_floats = (size_t)HW * NCH;  // 39.32 M floats = 157.3 MB

  // sorted layout: pts_s, fref_s, tmap
  size_t pts_off  = (int_end + 15) & ~(size_t)15;
  size_t fref_off = (pts_off + (size_t)3 * N * 4 + 15) & ~(size_t)15;
  size_t tmap_s_off = (fref_off + (size_t)N * NCH * 4 + 15) & ~(size_t)15;
  const size_t need_sorted = tmap_s_off + 3 * map_floats * 4 + 256;
  // plain layout: tmap right after ints
  size_t tmap_p_off = (int_end + 15) & ~(size_t)15;
  const size_t need_plain = tmap_p_off + 3 * map_floats * 4 + 256;

  float* out = (float*)d_out;

  init_kernel<<<10, 512, 0, stream>>>(Rin, tin, st, hist);

  if (ws_size >= need_sorted) {
    float* pts_s  = (float*)((char*)d_ws + pts_off);
    float* fref_s = (float*)((char*)d_ws + fref_off);
    float* tmap   = (float*)((char*)d_ws + tmap_s_off);
    const int npb = (N + 255) / 256;
    sort_key_kernel<<<npb, 256, 0, stream>>>(pts, Rin, tin, Kmat, keys, hist, N);
    sort_scan_kernel<<<1, 512, 0, stream>>>(hist, offs);
    sort_scatter_kernel<<<npb, 256, 0, stream>>>(keys, offs, order, N);
    permute_kernel<<<1024, 256, 0, stream>>>(pts, fref, order, pts_s, fref_s, N);
    transpose3_kernel<<<NTILE, 512, 0, stream>>>(fm, gxm, gym, tmap);
    fused_kernel<true><<<GBLK, THREADS, 0, stream>>>(pts_s, fref_s, tmap, tmap,
                                                     tmap, Kmat, st, part, N);
    update_solve_kernel<<<1, 512, 0, stream>>>(part, GBLK, st, out, 1);
    for (int it = 0; it < 10; ++it) {
      fused_kernel<true><<<GBLK, THREADS, 0, stream>>>(pts_s, fref_s, tmap, tmap,
                                                       tmap, Kmat, st, part, N);
      update_solve_kernel<<<1, 512, 0, stream>>>(part, GBLK, st, out, 0);
    }
  } else if (ws_size >= need_plain) {
    float* tmap = (float*)((char*)d_ws + tmap_p_off);
    transpose3_kernel<<<NTILE, 512, 0, stream>>>(fm, gxm, gym, tmap);
    fused_kernel<true><<<GBLK, THREADS, 0, stream>>>(pts, fref, tmap, tmap,
                                                     tmap, Kmat, st, part, N);
    update_solve_kernel<<<1, 512, 0, stream>>>(part, GBLK, st, out, 1);
    for (int it = 0; it < 10; ++it) {
      fused_kernel<true><<<GBLK, THREADS, 0, stream>>>(pts, fref, tmap, tmap,
                                                       tmap, Kmat, st, part, N);
      update_solve_kernel<<<1, 512, 0, stream>>>(part, GBLK, st, out, 0);
    }
  } else {
    fused_kernel<false><<<GBLK, THREADS, 0, stream>>>(pts, fref, fm, gxm, gym,
                                                      Kmat, st, part, N);
    update_solve_kernel<<<1, 512, 0, stream>>>(part, GBLK, st, out, 1);
    for (int it = 0; it < 10; ++it) {
      fused_kernel<false><<<GBLK, THREADS, 0, stream>>>(pts, fref, fm, gxm, gym,
                                                        Kmat, st, part, N);
      update_solve_kernel<<<1, 512, 0, stream>>>(part, GBLK, st, out, 0);
    }
  }
}